// Round 4
// baseline (81.355 us; speedup 1.0000x reference)
//
#include <hip/hip_runtime.h>
#include <math.h>

#define HDIM 512
#define NH   32
#define LTOT 8192
#define CHUNK 8     // consecutive l per thread (4 packed pairs)
#define TPB  256
#define NBANDS 16   // 16 bands x 512 l each per h
#define BANDL  512

typedef float v2f __attribute__((ext_vector_type(2)));

// One h is covered by 4 blocks x 4 waves = 16 wave-bands of 512 l.
// LOAD BALANCE is the point of this version (round-4):
//  - Work per l decays strongly (pole skip threshold), so contiguous l-quarters
//    made block cost wildly asymmetric, AND the heavy blocks all landed on a
//    subset of XCDs (heavy q=0 had bid%4==0 -> XCDs {0,4} only). End-of-kernel
//    waited on those stragglers; kernel-internal tweaks (r1 prefetch, r3
//    occupancy) were invisible because imbalance set the critical path.
//  - Fix A: wave w of block (h,q) handles band 4w+q -> every block owns a
//    stride-4 sample of the decay profile (near-identical block cost).
//  - Fix B: bid = q*HDIM + h -> any residual q-asymmetry round-robins across
//    all 8 XCDs instead of clustering.
__global__ __launch_bounds__(TPB, 8) void s4_kernel(
    const float* __restrict__ log_dt,
    const float* __restrict__ log_A_real,
    const float* __restrict__ A_imag,
    const float* __restrict__ Bmat,
    const float* __restrict__ Cmat,
    float* __restrict__ out)
{
    __shared__ float4 p0[NH]; // re*log2e, im/(2pi), a2=2Re(w^2), b2=|w|^4
    __shared__ float4 p1[NH]; // E0r, E1r, E0i, E1i   (Ej = 2*Ceff*w^j)
    __shared__ float4 p2[NH]; // E2r, E3r, E2i, E3i

    const int bid  = blockIdx.x;
    const int h    = bid & (HDIM - 1);   // q-major ordering: bid = q*HDIM + h
    const int q    = bid >> 9;
    const int tid  = threadIdx.x;

    if (tid < NH) {
        const int n   = tid;
        const int idx = h * NH + n;
        const float dt = expf(log_dt[h]);
        const float Ar = -expf(log_A_real[idx]);   // A = -exp(lar) - i*A_imag
        const float Ai = -A_imag[idx];
        const float re = Ar * dt;                  // dtA (re < 0)
        const float im = Ai * dt;
        float sw, cw;
        sincosf(im, &sw, &cw);                     // precise: small arg
        const float er = expf(re);
        const float wr = er * cw;                  // w = exp(dtA)
        const float wi = er * sw;
        // (w - 1) / A
        const float inv = 1.0f / (Ar * Ar + Ai * Ai);
        const float nr = wr - 1.0f, ni = wi;
        const float qr = (nr * Ar + ni * Ai) * inv;
        const float qi = (ni * Ar - nr * Ai) * inv;
        // E0 = 2 * Bc * Cc * (w-1)/A
        const float Br = Bmat[2 * idx], Bi = Bmat[2 * idx + 1];
        const float Cr = Cmat[2 * idx], Ci = Cmat[2 * idx + 1];
        const float bcr = Br * Cr - Bi * Ci;
        const float bci = Br * Ci + Bi * Cr;
        const float e0r = 2.0f * (bcr * qr - bci * qi);
        const float e0i = 2.0f * (bcr * qi + bci * qr);
        // Ej = E0 * w^j
        const float e1r = e0r * wr - e0i * wi, e1i = e0r * wi + e0i * wr;
        const float e2r = e1r * wr - e1i * wi, e2i = e1r * wi + e1i * wr;
        const float e3r = e2r * wr - e2i * wi, e3i = e2r * wi + e2i * wr;
        const float b1 = er * er;                  // |w|^2
        p0[n] = make_float4(re * 1.44269504089f, im * 0.15915494309f,
                            2.0f * (wr * wr - wi * wi), b1 * b1);
        p1[n] = make_float4(e0r, e1r, e0i, e1i);
        p2[n] = make_float4(e2r, e3r, e2i, e3i);
    }
    __syncthreads();

    const int wave = tid >> 6;
    const int lane = tid & 63;
    const int band = wave * 4 + q;               // stride-4 decay sampling
    const int l0   = band * BANDL + lane * CHUNK;
    const float l0f = (float)l0;

    v2f acc2[CHUNK / 2];
#pragma unroll
    for (int k = 0; k < CHUNK / 2; ++k) acc2[k] = v2f{0.0f, 0.0f};

#pragma unroll 1
    for (int n = 0; n < NH; ++n) {
        const float4 P0 = p0[n];
        const float ax2 = P0.x * l0f;          // re*log2e*l0  (<= 0)
        if (ax2 < -43.3f) continue;            // 2^-43.3 ~ 1e-13: negligible
        const float4 Q1 = p1[n];
        const float4 Q2 = p2[n];
        float ph = P0.y * l0f;                 // phase in revolutions
        ph = __builtin_amdgcn_fractf(ph);
        const float s = __builtin_amdgcn_sinf(ph);   // sin(2*pi*ph)
        const float c = __builtin_amdgcn_cosf(ph);
        const float e = __builtin_amdgcn_exp2f(ax2); // e^{re*l0}
        const float kr = e * c;                // K(l0) = exp(dtA*l0)
        const float ki = e * s;
        // seeds: Pa = (u0,u1), Pb = (u2,u3);  u_j = Re(Ej * K)
        v2f Pa = v2f{Q1.x, Q1.y} * kr - v2f{Q1.z, Q1.w} * ki;
        v2f Pb = v2f{Q2.x, Q2.y} * kr - v2f{Q2.z, Q2.w} * ki;
        acc2[0] += Pa;
        acc2[1] += Pb;
        const v2f a2 = v2f{P0.z, P0.z};
        const v2f b2 = v2f{P0.w, P0.w};
#pragma unroll
        for (int k = 2; k < CHUNK / 2; ++k) {
            const v2f Pn = a2 * Pb - b2 * Pa;  // packed: pk_mul + pk_fma
            acc2[k] += Pn;
            Pa = Pb;
            Pb = Pn;
        }
    }

    float4* o = (float4*)(out + (size_t)h * LTOT + l0);
#pragma unroll
    for (int j = 0; j < CHUNK / 4; ++j)
        o[j] = make_float4(acc2[2 * j].x, acc2[2 * j].y,
                           acc2[2 * j + 1].x, acc2[2 * j + 1].y);
}

extern "C" void kernel_launch(void* const* d_in, const int* in_sizes, int n_in,
                              void* d_out, int out_size, void* d_ws, size_t ws_size,
                              hipStream_t stream)
{
    (void)in_sizes; (void)n_in; (void)d_ws; (void)ws_size; (void)out_size;
    const float* log_dt     = (const float*)d_in[0];
    const float* log_A_real = (const float*)d_in[1];
    const float* A_imag     = (const float*)d_in[2];
    const float* Bmat       = (const float*)d_in[3];
    const float* Cmat       = (const float*)d_in[4];
    float* out = (float*)d_out;

    s4_kernel<<<dim3(HDIM * 4), dim3(TPB), 0, stream>>>(
        log_dt, log_A_real, A_imag, Bmat, Cmat, out);
}